// Round 1
// 280.401 us; speedup vs baseline: 1.1352x; 1.1352x over previous
//
#include <hip/hip_runtime.h>
#include <stdint.h>

typedef __bf16 bf16x8 __attribute__((ext_vector_type(8)));
typedef float f32x4 __attribute__((ext_vector_type(4)));

__device__ __forceinline__ unsigned int f2bf(float f) {
  unsigned int u = __float_as_uint(f);
  return (u + 0x7fffu + ((u >> 16) & 1u)) >> 16;  // RNE
}
__device__ __forceinline__ unsigned int pack2(float a, float b) {
  return f2bf(a) | (f2bf(b) << 16);
}

// In-register 16-point FWHT (4 stages, fully unrolled)
__device__ __forceinline__ void fwht16(float v[16]) {
#pragma unroll
  for (int s = 0; s < 4; ++s) {
    const int h = 1 << s;
#pragma unroll
    for (int i = 0; i < 16; ++i) {
      if (!(i & h)) {
        float a = v[i], b = v[i ^ h];
        v[i] = a + b;
        v[i ^ h] = a - b;
      }
    }
  }
}

#define LP(i) ((i) + ((i) >> 5))  // padded LDS index: +1 float per 32

// ---------------------------------------------------------------------------
// K1: per-row  FWHT(4096)(x*SU) * (1/64) -> bf16
// ---------------------------------------------------------------------------
__global__ void __launch_bounds__(256) k_fwht_in(const float* __restrict__ X,
                                                 const float* __restrict__ SU,
                                                 unsigned short* __restrict__ Xh) {
  __shared__ float lds[4224];  // 4096 + 128 pad
  const int t = threadIdx.x;
  const size_t row = blockIdx.x;
  const float4* xr = (const float4*)(X + row * 4096);
  const float4* su = (const float4*)SU;
  float v[16];
#pragma unroll
  for (int q = 0; q < 4; ++q) {
    float4 a = xr[4 * t + q], s = su[4 * t + q];
    v[4 * q + 0] = a.x * s.x;
    v[4 * q + 1] = a.y * s.y;
    v[4 * q + 2] = a.z * s.z;
    v[4 * q + 3] = a.w * s.w;
  }
  fwht16(v);  // bits 0-3
#pragma unroll
  for (int q = 0; q < 4; ++q) {
    int i0 = 16 * t + 4 * q;
    *(float4*)&lds[LP(i0)] = make_float4(v[4 * q], v[4 * q + 1], v[4 * q + 2], v[4 * q + 3]);
  }
  __syncthreads();
  const int b = ((t >> 4) << 8) | (t & 15);
#pragma unroll
  for (int j = 0; j < 16; ++j) { int i = b + 16 * j; v[j] = lds[LP(i)]; }
  fwht16(v);  // bits 4-7
#pragma unroll
  for (int j = 0; j < 16; ++j) { int i = b + 16 * j; lds[LP(i)] = v[j]; }
  __syncthreads();
#pragma unroll
  for (int j = 0; j < 16; ++j) { int i = t + 256 * j; v[j] = lds[LP(i)]; }
  fwht16(v);  // bits 8-11
  unsigned short* orow = Xh + row * 4096;
#pragma unroll
  for (int j = 0; j < 16; ++j)
    orow[t + 256 * j] = (unsigned short)f2bf(v[j] * 0.015625f);
}

// ---------------------------------------------------------------------------
// K2: W[m][k] (bf16) = grid[Qidxs[m][k/8]][k%8]
// ---------------------------------------------------------------------------
__global__ void __launch_bounds__(256) k_decompress(const int* __restrict__ Qidxs,
                                                    const float* __restrict__ G,
                                                    unsigned short* __restrict__ Wh) {
  int e = blockIdx.x * 256 + threadIdx.x;
  int idx = Qidxs[e];
  const float4* g = (const float4*)(G + (size_t)idx * 8);
  float4 a = g[0], b = g[1];
  uint4 o;
  o.x = pack2(a.x, a.y);
  o.y = pack2(a.z, a.w);
  o.z = pack2(b.x, b.y);
  o.w = pack2(b.z, b.w);
  ((uint4*)Wh)[e] = o;
}

// ---------------------------------------------------------------------------
// K3: GEMM C = A @ B^T (both bf16 [4096][4096], K-major), fp32 out.
// 256x256 tile, BK=64, 8 waves (2Mx4N), 8-phase schedule with counted vmcnt
// (T2 XOR-swizzle + T3/T4 phase interleave + T5 setprio).
//
// Pipeline invariants (race-freedom):
//  - tile g lives in buf[g&1]; B region consumed at end of phase 0 of its
//    group, A region at end of phase 3.
//  - group g stages A(g+1)->buf[(g+1)&1] at phases 0,1 (that buffer's A was
//    last read in group g-1, barrier-separated) and B(g+2)->buf[g&1] at
//    phases 2,3 (B of tile g consumed at phase 0; >=1 phase margin).
//  - vmcnt(4) once per group (never 0): leaves the two B(g+1) half-tiles
//    (2 loads/wave each) in flight across the group boundary; everything
//    older (all of tile g+1's A+B) has landed; barrier makes it global.
// ---------------------------------------------------------------------------
__device__ __forceinline__ void gl2lds16(const unsigned short* g, unsigned short* l) {
  __builtin_amdgcn_global_load_lds(
      (const __attribute__((address_space(1))) void*)g,
      (__attribute__((address_space(3))) void*)l, 16, 0, 0);
}

#define BARX() __builtin_amdgcn_s_barrier()
#define SCHEDB() __builtin_amdgcn_sched_barrier(0)
#define WAITL0() asm volatile("s_waitcnt lgkmcnt(0)" ::: "memory")
#define WAITV4() asm volatile("s_waitcnt vmcnt(4)" ::: "memory")

// One compute phase: read A-quadrant q (4x ds_read_b128), issue one staging
// half-tile (STMT), barrier, wait own LDS reads, 16 MFMAs, optional TAIL
// (vmcnt), barrier.  bq[][] (B frags) are read once in phase 0 and held.
#define APHASE(q, STMT, TAIL)                                                   \
  {                                                                             \
    bf16x8 af[2][2];                                                            \
    _Pragma("unroll") for (int mm = 0; mm < 2; ++mm)                            \
        _Pragma("unroll") for (int kh = 0; kh < 2; ++kh)                        \
            af[mm][kh] = *(const bf16x8*)&sAp[((wr << 7) + (((q)*2 + mm) << 4) + frow) * 64 + \
                                              ((((kh << 2) + jb) ^ sw) << 3)];  \
    STMT;                                                                       \
    BARX();                                                                     \
    WAITL0();                                                                   \
    SCHEDB();                                                                   \
    __builtin_amdgcn_s_setprio(1);                                              \
    _Pragma("unroll") for (int mm = 0; mm < 2; ++mm)                            \
        _Pragma("unroll") for (int n = 0; n < 4; ++n)                           \
            _Pragma("unroll") for (int kh = 0; kh < 2; ++kh)                    \
                acc[(q)*2 + mm][n] = __builtin_amdgcn_mfma_f32_16x16x32_bf16(   \
                    af[mm][kh], bq[n][kh], acc[(q)*2 + mm][n], 0, 0, 0);        \
    __builtin_amdgcn_s_setprio(0);                                              \
    TAIL;                                                                       \
    BARX();                                                                     \
    SCHEDB();                                                                   \
  }

__global__ void __launch_bounds__(512, 2)
k_gemm_bt(const unsigned short* __restrict__ A,
          const unsigned short* __restrict__ B,
          float* __restrict__ C) {
  const int K = 4096, N = 4096;
  __shared__ unsigned short sA[2][256 * 64];
  __shared__ unsigned short sB[2][256 * 64];
  const int tid = threadIdx.x;
  const int lane = tid & 63;
  const int wave = tid >> 6;
  const int wr = wave >> 2;  // 0..1  (M half)
  const int wc = wave & 3;   // 0..3  (N quarter)
  const int frow = lane & 15;
  const int jb = lane >> 4;  // 0..3
  const int sw = frow & 7;   // XOR swizzle key (row&7 == frow&7 for all frag rows)
  const int bn = blockIdx.x, bm = blockIdx.y;
  const size_t rowA0 = (size_t)bm * 256;
  const size_t rowB0 = (size_t)bn * 256;

  f32x4 acc[8][4] = {};

  // stage one half-tile (h = 0/1 -> rows h*128..h*128+127) of K-tile `ktile`
  // into `dst` (tile base). LDS dest is linear (wave-uniform base + lane*16);
  // the XOR swizzle is applied to the GLOBAL source chunk (m173 pattern).
  auto stage = [&](const unsigned short* __restrict__ G, size_t row0,
                   unsigned short* dst, int h, int ktile) {
    const int kt = (ktile < 64 ? ktile : 0) << 6;  // clamp: tiles >=64 load k=0, never read
#pragma unroll
    for (int l = 0; l < 2; ++l) {
      const int c = (l << 9) + tid;          // 0..1023
      const int r = c >> 3;                  // row within half: 0..127
      const int jg = (c & 7) ^ (r & 7);      // pre-swizzled global chunk
      gl2lds16(G + (row0 + (size_t)((h << 7) + r)) * K + kt + (jg << 3),
               dst + (h << 13) + (c << 3));
    }
  };

  // one 4-phase group: compute K-tile from buf p; stage A(gA)->buf p^1 and
  // B(gB)->buf p.
  auto group = [&](int p, int gA, int gB) {
    const unsigned short* sAp = sA[p];
    const unsigned short* sBp = sB[p];
    unsigned short* sAn = sA[p ^ 1];
    unsigned short* sBn = sB[p];
    bf16x8 bq[4][2];
    // phase 0 reads ALL B fragments (8x ds_read_b128); B region of buf p is
    // fully consumed at this phase's closing barrier.
#pragma unroll
    for (int n = 0; n < 4; ++n)
#pragma unroll
      for (int kh = 0; kh < 2; ++kh)
        bq[n][kh] = *(const bf16x8*)&sBp[((wc << 6) + (n << 4) + frow) * 64 +
                                         ((((kh << 2) + jb) ^ sw) << 3)];
    APHASE(0, (stage(A, rowA0, sAn, 0, gA)), ((void)0));
    APHASE(1, (stage(A, rowA0, sAn, 1, gA)), ((void)0));
    APHASE(2, (stage(B, rowB0, sBn, 0, gB)), ((void)0));
    APHASE(3, (stage(B, rowB0, sBn, 1, gB)), WAITV4());
  };

  // prologue: tile0 (B then A) -> buf0, B(1) -> buf1; wait so tile0 landed,
  // leaving B(1)'s 4 loads in flight (steady-state invariant).
  stage(B, rowB0, sB[0], 0, 0);
  stage(B, rowB0, sB[0], 1, 0);
  stage(A, rowA0, sA[0], 0, 0);
  stage(A, rowA0, sA[0], 1, 0);
  stage(B, rowB0, sB[1], 0, 1);
  stage(B, rowB0, sB[1], 1, 1);
  WAITV4();
  BARX();
  SCHEDB();

#pragma unroll 1
  for (int i = 0; i < 32; ++i) {
    group(0, 2 * i + 1, 2 * i + 2);
    group(1, 2 * i + 2, 2 * i + 3);
  }

  // epilogue: C/D layout col = lane&15, row = (lane>>4)*4 + reg
  const int rbase = bm * 256 + (wr << 7) + (jb << 2);
  const int cbase = bn * 256 + (wc << 6) + frow;
#pragma unroll
  for (int m = 0; m < 8; ++m)
#pragma unroll
    for (int n = 0; n < 4; ++n) {
      float* cp = C + (size_t)(rbase + (m << 4)) * N + cbase + (n << 4);
#pragma unroll
      for (int r = 0; r < 4; ++r) cp[(size_t)r * N] = acc[m][n][r];
    }
}

// ---------------------------------------------------------------------------
// K4: per-row FWHT(4096) on fp32 output ; * SV * (1/64)
// ---------------------------------------------------------------------------
__global__ void __launch_bounds__(256) k_fwht_out(float* __restrict__ Y,
                                                  const float* __restrict__ SV) {
  __shared__ float lds[4224];
  const int t = threadIdx.x;
  const size_t row = blockIdx.x;
  float* yrow = Y + row * 4096;
  const float4* yr = (const float4*)yrow;
  float v[16];
#pragma unroll
  for (int q = 0; q < 4; ++q) {
    float4 a = yr[4 * t + q];
    v[4 * q + 0] = a.x;
    v[4 * q + 1] = a.y;
    v[4 * q + 2] = a.z;
    v[4 * q + 3] = a.w;
  }
  fwht16(v);  // bits 0-3
#pragma unroll
  for (int q = 0; q < 4; ++q) {
    int i0 = 16 * t + 4 * q;
    *(float4*)&lds[LP(i0)] = make_float4(v[4 * q], v[4 * q + 1], v[4 * q + 2], v[4 * q + 3]);
  }
  __syncthreads();
  const int b = ((t >> 4) << 8) | (t & 15);
#pragma unroll
  for (int j = 0; j < 16; ++j) { int i = b + 16 * j; v[j] = lds[LP(i)]; }
  fwht16(v);  // bits 4-7
#pragma unroll
  for (int j = 0; j < 16; ++j) { int i = b + 16 * j; lds[LP(i)] = v[j]; }
  __syncthreads();
#pragma unroll
  for (int j = 0; j < 16; ++j) { int i = t + 256 * j; v[j] = lds[LP(i)]; }
  fwht16(v);  // bits 8-11
#pragma unroll
  for (int j = 0; j < 16; ++j) {
    int i = t + 256 * j;
    yrow[i] = v[j] * SV[i] * 0.015625f;
  }
}

// ---------------------------------------------------------------------------
extern "C" void kernel_launch(void* const* d_in, const int* in_sizes, int n_in,
                              void* d_out, int out_size, void* d_ws, size_t ws_size,
                              hipStream_t stream) {
  const float* X     = (const float*)d_in[0];
  const float* SU    = (const float*)d_in[1];
  const float* SV    = (const float*)d_in[2];
  const float* G     = (const float*)d_in[3];
  const int*   Qidxs = (const int*)d_in[4];
  float* out = (float*)d_out;

  unsigned short* Xh = (unsigned short*)d_ws;
  unsigned short* Wh = Xh + (size_t)4096 * 4096;

  k_fwht_in<<<4096, 256, 0, stream>>>(X, SU, Xh);
  k_decompress<<<(4096 * 512) / 256, 256, 0, stream>>>(Qidxs, G, Wh);
  k_gemm_bt<<<dim3(16, 16), 512, 0, stream>>>(Xh, Wh, out);
  k_fwht_out<<<4096, 256, 0, stream>>>(out, SV);
}

// Round 2
// 271.977 us; speedup vs baseline: 1.1703x; 1.0310x over previous
//
#include <hip/hip_runtime.h>
#include <stdint.h>

typedef __bf16 bf16x8 __attribute__((ext_vector_type(8)));
typedef float f32x4 __attribute__((ext_vector_type(4)));

__device__ __forceinline__ unsigned int f2bf(float f) {
  unsigned int u = __float_as_uint(f);
  return (u + 0x7fffu + ((u >> 16) & 1u)) >> 16;  // RNE
}
__device__ __forceinline__ unsigned int pack2(float a, float b) {
  return f2bf(a) | (f2bf(b) << 16);
}

// In-register 16-point FWHT (4 stages, fully unrolled)
__device__ __forceinline__ void fwht16(float v[16]) {
#pragma unroll
  for (int s = 0; s < 4; ++s) {
    const int h = 1 << s;
#pragma unroll
    for (int i = 0; i < 16; ++i) {
      if (!(i & h)) {
        float a = v[i], b = v[i ^ h];
        v[i] = a + b;
        v[i ^ h] = a - b;
      }
    }
  }
}

#define LP(i) ((i) + ((i) >> 5))  // padded LDS index: +1 float per 32

// ---------------------------------------------------------------------------
// K1: per-row  FWHT(4096)(x*SU) * (1/64) -> bf16
// ---------------------------------------------------------------------------
__global__ void __launch_bounds__(256) k_fwht_in(const float* __restrict__ X,
                                                 const float* __restrict__ SU,
                                                 unsigned short* __restrict__ Xh) {
  __shared__ float lds[4224];  // 4096 + 128 pad
  const int t = threadIdx.x;
  const size_t row = blockIdx.x;
  const float4* xr = (const float4*)(X + row * 4096);
  const float4* su = (const float4*)SU;
  float v[16];
#pragma unroll
  for (int q = 0; q < 4; ++q) {
    float4 a = xr[4 * t + q], s = su[4 * t + q];
    v[4 * q + 0] = a.x * s.x;
    v[4 * q + 1] = a.y * s.y;
    v[4 * q + 2] = a.z * s.z;
    v[4 * q + 3] = a.w * s.w;
  }
  fwht16(v);  // bits 0-3
#pragma unroll
  for (int q = 0; q < 4; ++q) {
    int i0 = 16 * t + 4 * q;
    *(float4*)&lds[LP(i0)] = make_float4(v[4 * q], v[4 * q + 1], v[4 * q + 2], v[4 * q + 3]);
  }
  __syncthreads();
  const int b = ((t >> 4) << 8) | (t & 15);
#pragma unroll
  for (int j = 0; j < 16; ++j) { int i = b + 16 * j; v[j] = lds[LP(i)]; }
  fwht16(v);  // bits 4-7
#pragma unroll
  for (int j = 0; j < 16; ++j) { int i = b + 16 * j; lds[LP(i)] = v[j]; }
  __syncthreads();
#pragma unroll
  for (int j = 0; j < 16; ++j) { int i = t + 256 * j; v[j] = lds[LP(i)]; }
  fwht16(v);  // bits 8-11
  unsigned short* orow = Xh + row * 4096;
#pragma unroll
  for (int j = 0; j < 16; ++j)
    orow[t + 256 * j] = (unsigned short)f2bf(v[j] * 0.015625f);
}

// ---------------------------------------------------------------------------
// K2: W[m][k] (bf16) = grid[Qidxs[m][k/8]][k%8]
// ---------------------------------------------------------------------------
__global__ void __launch_bounds__(256) k_decompress(const int* __restrict__ Qidxs,
                                                    const float* __restrict__ G,
                                                    unsigned short* __restrict__ Wh) {
  int e = blockIdx.x * 256 + threadIdx.x;
  int idx = Qidxs[e];
  const float4* g = (const float4*)(G + (size_t)idx * 8);
  float4 a = g[0], b = g[1];
  uint4 o;
  o.x = pack2(a.x, a.y);
  o.y = pack2(a.z, a.w);
  o.z = pack2(b.x, b.y);
  o.w = pack2(b.z, b.w);
  ((uint4*)Wh)[e] = o;
}

// ---------------------------------------------------------------------------
// K3: GEMM C = A @ B^T (both bf16 [4096][4096], K-major), fp32 out.
// 256x256 tile, BK=64, 8 waves (2Mx4N), 4-phase groups with SINGLE-M
// SOFTWARE-PIPELINED fragment reads: ds_reads for m-step j+1 issue before /
// between the MFMA batches of m-step j, so the LDS drain hides under MFMA
// (compiler emits counted lgkmcnt). Only phase 0's B+A0 burst is exposed.
//
// vmcnt discipline (per wave, 2 loads per stage call; group g, buf p=g&1):
//   entry invariant: 4 outstanding = B(g+1) [staged prev group ph2,3]
//   ph0 stage A(g+1)h0 -> 6 ; ph1 stage A(g+1)h1 -> 8 ; vmcnt(4) retires B(g+1)
//   ph2 stage B(g+2)h0 -> 6 ; vmcnt(2) retires A(g+1)
//   ph3 stage B(g+2)h1 -> 4 ; exit with 4 = B(g+2)  [invariant restored]
// Visibility: B(g+1) retired@ph1 + ph1-closing barrier -> read next group ph0.
//             A(g+1) retired@ph2 + ph2-closing barrier -> read next group ph0.
// WAR: stage A(g+1) (ph0/1) overwrites buf p^1 A-region, last read by group
//      g-1's pre-ph3-barrier ds_reads (lgkm-complete before its closing
//      barrier). stage B(g+2) (ph2/3) overwrites buf p B-region, last read
//      at group g ph0 (drained before ph0's MFMA). All barrier-separated.
// ---------------------------------------------------------------------------
__device__ __forceinline__ void gl2lds16(const unsigned short* g, unsigned short* l) {
  __builtin_amdgcn_global_load_lds(
      (const __attribute__((address_space(1))) void*)g,
      (__attribute__((address_space(3))) void*)l, 16, 0, 0);
}

#define BARX() __builtin_amdgcn_s_barrier()
#define SCHEDB() __builtin_amdgcn_sched_barrier(0)
#define WAITV4() asm volatile("s_waitcnt vmcnt(4)" ::: "memory")
#define WAITV2() asm volatile("s_waitcnt vmcnt(2)" ::: "memory")

// fragment loads (plain loads -> compiler-managed counted lgkmcnt)
#define RD_A(dst, mm)                                                          \
  _Pragma("unroll") for (int kh = 0; kh < 2; ++kh)                             \
      dst[kh] = *(const bf16x8*)&sAp[(((wr) << 7) + ((mm) << 4) + frow) * 64 + \
                                     ((((kh << 2) + jb) ^ sw) << 3)];
#define RD_B()                                                                 \
  _Pragma("unroll") for (int n = 0; n < 4; ++n)                                \
      _Pragma("unroll") for (int kh = 0; kh < 2; ++kh)                         \
          bq[n][kh] = *(const bf16x8*)&sBp[(((wc) << 6) + (n << 4) + frow) * 64 + \
                                           ((((kh << 2) + jb) ^ sw) << 3)];
#define MF(mm, buf)                                                            \
  _Pragma("unroll") for (int n = 0; n < 4; ++n)                                \
      _Pragma("unroll") for (int kh = 0; kh < 2; ++kh)                         \
          acc[(mm)][n] = __builtin_amdgcn_mfma_f32_16x16x32_bf16(              \
              buf[kh], bq[n][kh], acc[(mm)][n], 0, 0, 0);

__global__ void __launch_bounds__(512, 2)
k_gemm_bt(const unsigned short* __restrict__ A,
          const unsigned short* __restrict__ B,
          float* __restrict__ C) {
  const int K = 4096, N = 4096;
  __shared__ unsigned short sA[2][256 * 64];
  __shared__ unsigned short sB[2][256 * 64];
  const int tid = threadIdx.x;
  const int lane = tid & 63;
  const int wave = tid >> 6;
  const int wr = wave >> 2;  // 0..1  (M half)
  const int wc = wave & 3;   // 0..3  (N quarter)
  const int frow = lane & 15;
  const int jb = lane >> 4;  // 0..3
  const int sw = frow & 7;   // XOR swizzle key
  const int bn = blockIdx.x, bm = blockIdx.y;
  const size_t rowA0 = (size_t)bm * 256;
  const size_t rowB0 = (size_t)bn * 256;

  f32x4 acc[8][4] = {};

  // stage one half-tile (h=0/1 -> rows h*128..h*128+127) of K-tile `ktile`.
  // LDS dest linear (wave-uniform base + lane*16); XOR swizzle applied to the
  // GLOBAL source chunk (m173 pattern).
  auto stage = [&](const unsigned short* __restrict__ G, size_t row0,
                   unsigned short* dst, int h, int ktile) {
    const int kt = (ktile < 64 ? ktile : 0) << 6;  // clamp: tiles >=64 load k=0, never read
#pragma unroll
    for (int l = 0; l < 2; ++l) {
      const int c = (l << 9) + tid;          // 0..1023
      const int r = c >> 3;                  // row within half: 0..127
      const int jg = (c & 7) ^ (r & 7);      // pre-swizzled global chunk
      gl2lds16(G + (row0 + (size_t)((h << 7) + r)) * K + kt + (jg << 3),
               dst + (h << 13) + (c << 3));
    }
  };

  // one 4-phase group, m-step-pipelined (see header comment for invariants)
  auto group = [&](int p, int gA, int gB) {
    const unsigned short* sAp = sA[p];
    const unsigned short* sBp = sB[p];
    unsigned short* sAn = (unsigned short*)sA[p ^ 1];
    unsigned short* sBn = (unsigned short*)sB[p];
    bf16x8 bq[4][2];
    bf16x8 aX[2], aY[2];
    // ---- phase 0: exposed burst = bq + aX (10 reads); aY pipelined
    RD_B();
    RD_A(aX, 0);
    RD_A(aY, 1);
    stage(A, rowA0, sAn, 0, gA);
    BARX(); SCHEDB();
    __builtin_amdgcn_s_setprio(1);
    MF(0, aX);        // compiler waits bq+aX (counted; aY still in flight)
    RD_A(aX, 2);      // reload under MF(1)
    MF(1, aY);
    __builtin_amdgcn_s_setprio(0);
    BARX(); SCHEDB();
    // ---- phase 1
    RD_A(aY, 3);
    stage(A, rowA0, sAn, 1, gA);
    BARX(); SCHEDB();
    __builtin_amdgcn_s_setprio(1);
    MF(2, aX);
    RD_A(aX, 4);
    MF(3, aY);
    __builtin_amdgcn_s_setprio(0);
    WAITV4(); SCHEDB();   // retire B(g+1) staging
    BARX(); SCHEDB();
    // ---- phase 2
    RD_A(aY, 5);
    stage(B, rowB0, sBn, 0, gB);
    BARX(); SCHEDB();
    __builtin_amdgcn_s_setprio(1);
    MF(4, aX);
    RD_A(aX, 6);
    MF(5, aY);
    __builtin_amdgcn_s_setprio(0);
    WAITV2(); SCHEDB();   // retire A(g+1) staging
    BARX(); SCHEDB();
    // ---- phase 3
    RD_A(aY, 7);
    stage(B, rowB0, sBn, 1, gB);
    BARX(); SCHEDB();
    __builtin_amdgcn_s_setprio(1);
    MF(6, aX);
    MF(7, aY);
    __builtin_amdgcn_s_setprio(0);
    BARX(); SCHEDB();
  };

  // prologue: tile0 (B then A) -> buf0, B(1) -> buf1; vmcnt(4) leaves B(1)'s
  // 4 loads in flight (steady-state entry invariant).
  stage(B, rowB0, sB[0], 0, 0);
  stage(B, rowB0, sB[0], 1, 0);
  stage(A, rowA0, sA[0], 0, 0);
  stage(A, rowA0, sA[0], 1, 0);
  stage(B, rowB0, sB[1], 0, 1);
  stage(B, rowB0, sB[1], 1, 1);
  WAITV4();
  BARX();
  SCHEDB();

#pragma unroll 1
  for (int i = 0; i < 32; ++i) {
    group(0, 2 * i + 1, 2 * i + 2);
    group(1, 2 * i + 2, 2 * i + 3);
  }

  // epilogue: C/D layout col = lane&15, row = (lane>>4)*4 + reg
  const int rbase = bm * 256 + (wr << 7) + (jb << 2);
  const int cbase = bn * 256 + (wc << 6) + frow;
#pragma unroll
  for (int m = 0; m < 8; ++m)
#pragma unroll
    for (int n = 0; n < 4; ++n) {
      float* cp = C + (size_t)(rbase + (m << 4)) * N + cbase + (n << 4);
#pragma unroll
      for (int r = 0; r < 4; ++r) cp[(size_t)r * N] = acc[m][n][r];
    }
}

// ---------------------------------------------------------------------------
// K4: per-row FWHT(4096) on fp32 output ; * SV * (1/64)
// ---------------------------------------------------------------------------
__global__ void __launch_bounds__(256) k_fwht_out(float* __restrict__ Y,
                                                  const float* __restrict__ SV) {
  __shared__ float lds[4224];
  const int t = threadIdx.x;
  const size_t row = blockIdx.x;
  float* yrow = Y + row * 4096;
  const float4* yr = (const float4*)yrow;
  float v[16];
#pragma unroll
  for (int q = 0; q < 4; ++q) {
    float4 a = yr[4 * t + q];
    v[4 * q + 0] = a.x;
    v[4 * q + 1] = a.y;
    v[4 * q + 2] = a.z;
    v[4 * q + 3] = a.w;
  }
  fwht16(v);  // bits 0-3
#pragma unroll
  for (int q = 0; q < 4; ++q) {
    int i0 = 16 * t + 4 * q;
    *(float4*)&lds[LP(i0)] = make_float4(v[4 * q], v[4 * q + 1], v[4 * q + 2], v[4 * q + 3]);
  }
  __syncthreads();
  const int b = ((t >> 4) << 8) | (t & 15);
#pragma unroll
  for (int j = 0; j < 16; ++j) { int i = b + 16 * j; v[j] = lds[LP(i)]; }
  fwht16(v);  // bits 4-7
#pragma unroll
  for (int j = 0; j < 16; ++j) { int i = b + 16 * j; lds[LP(i)] = v[j]; }
  __syncthreads();
#pragma unroll
  for (int j = 0; j < 16; ++j) { int i = t + 256 * j; v[j] = lds[LP(i)]; }
  fwht16(v);  // bits 8-11
#pragma unroll
  for (int j = 0; j < 16; ++j) {
    int i = t + 256 * j;
    yrow[i] = v[j] * SV[i] * 0.015625f;
  }
}

// ---------------------------------------------------------------------------
extern "C" void kernel_launch(void* const* d_in, const int* in_sizes, int n_in,
                              void* d_out, int out_size, void* d_ws, size_t ws_size,
                              hipStream_t stream) {
  const float* X     = (const float*)d_in[0];
  const float* SU    = (const float*)d_in[1];
  const float* SV    = (const float*)d_in[2];
  const float* G     = (const float*)d_in[3];
  const int*   Qidxs = (const int*)d_in[4];
  float* out = (float*)d_out;

  unsigned short* Xh = (unsigned short*)d_ws;
  unsigned short* Wh = Xh + (size_t)4096 * 4096;

  k_fwht_in<<<4096, 256, 0, stream>>>(X, SU, Xh);
  k_decompress<<<(4096 * 512) / 256, 256, 0, stream>>>(Qidxs, G, Wh);
  k_gemm_bt<<<dim3(16, 16), 512, 0, stream>>>(Xh, Wh, out);
  k_fwht_out<<<4096, 256, 0, stream>>>(out, SV);
}

// Round 3
// 268.851 us; speedup vs baseline: 1.1839x; 1.0116x over previous
//
#include <hip/hip_runtime.h>
#include <stdint.h>

typedef __bf16 bf16x8 __attribute__((ext_vector_type(8)));
typedef float f32x4 __attribute__((ext_vector_type(4)));

__device__ __forceinline__ unsigned int f2bf(float f) {
  unsigned int u = __float_as_uint(f);
  return (u + 0x7fffu + ((u >> 16) & 1u)) >> 16;  // RNE
}
__device__ __forceinline__ unsigned int pack2(float a, float b) {
  return f2bf(a) | (f2bf(b) << 16);
}

// In-register 16-point FWHT (4 stages, fully unrolled)
__device__ __forceinline__ void fwht16(float v[16]) {
#pragma unroll
  for (int s = 0; s < 4; ++s) {
    const int h = 1 << s;
#pragma unroll
    for (int i = 0; i < 16; ++i) {
      if (!(i & h)) {
        float a = v[i], b = v[i ^ h];
        v[i] = a + b;
        v[i ^ h] = a - b;
      }
    }
  }
}

#define LP(i) ((i) + ((i) >> 5))  // padded LDS index: +1 float per 32

// ---------------------------------------------------------------------------
// K1+K2 merged ("prep"): blocks [0,4096) do per-row FWHT(4096)(x*SU)*(1/64)
// -> bf16 ; blocks [4096,12288) decompress W[m][k] = grid[Qidxs[m][k/8]][k%8].
// Independent producers for the GEMM; merging removes one launch gap and
// co-schedules streaming (K1) with gather latency (K2).
// ---------------------------------------------------------------------------
__global__ void __launch_bounds__(256) k_prep(const float* __restrict__ X,
                                              const float* __restrict__ SU,
                                              unsigned short* __restrict__ Xh,
                                              const int* __restrict__ Qidxs,
                                              const float* __restrict__ G,
                                              unsigned short* __restrict__ Wh) {
  __shared__ float lds[4224];  // 4096 + 128 pad (unused by decompress blocks)
  const int t = threadIdx.x;
  if (blockIdx.x >= 4096) {
    // ---- decompress ----
    int e = (blockIdx.x - 4096) * 256 + t;
    int idx = Qidxs[e];
    const float4* g = (const float4*)(G + (size_t)idx * 8);
    float4 a = g[0], b = g[1];
    uint4 o;
    o.x = pack2(a.x, a.y);
    o.y = pack2(a.z, a.w);
    o.z = pack2(b.x, b.y);
    o.w = pack2(b.z, b.w);
    ((uint4*)Wh)[e] = o;
    return;
  }
  // ---- FWHT-in ----
  const size_t row = blockIdx.x;
  const float4* xr = (const float4*)(X + row * 4096);
  const float4* su = (const float4*)SU;
  float v[16];
#pragma unroll
  for (int q = 0; q < 4; ++q) {
    float4 a = xr[4 * t + q], s = su[4 * t + q];
    v[4 * q + 0] = a.x * s.x;
    v[4 * q + 1] = a.y * s.y;
    v[4 * q + 2] = a.z * s.z;
    v[4 * q + 3] = a.w * s.w;
  }
  fwht16(v);  // bits 0-3
#pragma unroll
  for (int q = 0; q < 4; ++q) {
    int i0 = 16 * t + 4 * q;
    *(float4*)&lds[LP(i0)] = make_float4(v[4 * q], v[4 * q + 1], v[4 * q + 2], v[4 * q + 3]);
  }
  __syncthreads();
  const int b = ((t >> 4) << 8) | (t & 15);
#pragma unroll
  for (int j = 0; j < 16; ++j) { int i = b + 16 * j; v[j] = lds[LP(i)]; }
  fwht16(v);  // bits 4-7
#pragma unroll
  for (int j = 0; j < 16; ++j) { int i = b + 16 * j; lds[LP(i)] = v[j]; }
  __syncthreads();
#pragma unroll
  for (int j = 0; j < 16; ++j) { int i = t + 256 * j; v[j] = lds[LP(i)]; }
  fwht16(v);  // bits 8-11
  unsigned short* orow = Xh + row * 4096;
#pragma unroll
  for (int j = 0; j < 16; ++j)
    orow[t + 256 * j] = (unsigned short)f2bf(v[j] * 0.015625f);
}

// ---------------------------------------------------------------------------
// K3: GEMM C = A @ B^T (both bf16 [4096][4096], K-major), fp32 out.
// 256x256 tile, BK=64, 8 waves (2Mx4N). 4-phase groups, 3-buffer A-fragment
// ROTATION (2-MF-batch lookahead ~310cyc > LDS latency) so post-ph0 lgkm
// drains are counted no-ops; ONE vmcnt per K-tile (m201 discipline).
//
// vmcnt ledger (per wave, 2 loads/stage-call; group g, buf p=g&1):
//   entry: 4 outstanding = B(g+1)            [staged in group g-1 ph2,3]
//   ph0 +A(g+1)h0 -> 6 ; ph1 +A(g+1)h1 -> 8
//   ph2 +B(g+2)h0 -> 10; ph3 +B(g+2)h1 -> 12; vmcnt(4) retires 8 oldest
//     = B(g+1)(4) + A(g+1)(4); exit with 4 = B(g+2).  [invariant restored]
// Visibility: A(g+1),B(g+1) retired before group-g closing barrier -> all
//   waves may read them at group g+1 ph0.
// WAR: stage A(g+1)->buf p^1 A-region at ph0/1: last readers were group
//   g-1's A-frag ds_reads, lgkm-drained before g-1's closing barrier;
//   stage issued after that barrier. stage B(g+2)->buf p B-region at
//   ph2/3: last readers group-g ph0 bq reads, drained before ph0's closing
//   barrier. All barrier-separated.
// Reg-rotation hazards are compiler-managed (plain loads, static indices).
// ---------------------------------------------------------------------------
__device__ __forceinline__ void gl2lds16(const unsigned short* g, unsigned short* l) {
  __builtin_amdgcn_global_load_lds(
      (const __attribute__((address_space(1))) void*)g,
      (__attribute__((address_space(3))) void*)l, 16, 0, 0);
}

#define BARX() __builtin_amdgcn_s_barrier()
#define SCHEDB() __builtin_amdgcn_sched_barrier(0)
#define WAITV4() asm volatile("s_waitcnt vmcnt(4)" ::: "memory")

#define RD_A(dst, mm)                                                          \
  _Pragma("unroll") for (int kh = 0; kh < 2; ++kh)                             \
      dst[kh] = *(const bf16x8*)&sAp[(((wr) << 7) + ((mm) << 4) + frow) * 64 + \
                                     ((((kh << 2) + jb) ^ sw) << 3)];
#define RD_B()                                                                 \
  _Pragma("unroll") for (int n = 0; n < 4; ++n)                                \
      _Pragma("unroll") for (int kh = 0; kh < 2; ++kh)                         \
          bq[n][kh] = *(const bf16x8*)&sBp[(((wc) << 6) + (n << 4) + frow) * 64 + \
                                           ((((kh << 2) + jb) ^ sw) << 3)];
#define MF(mm, buf)                                                            \
  _Pragma("unroll") for (int n = 0; n < 4; ++n)                                \
      _Pragma("unroll") for (int kh = 0; kh < 2; ++kh)                         \
          acc[(mm)][n] = __builtin_amdgcn_mfma_f32_16x16x32_bf16(              \
              buf[kh], bq[n][kh], acc[(mm)][n], 0, 0, 0);

__global__ void __launch_bounds__(512, 2)
k_gemm_bt(const unsigned short* __restrict__ A,
          const unsigned short* __restrict__ B,
          float* __restrict__ C) {
  const int K = 4096, N = 4096;
  __shared__ unsigned short sA[2][256 * 64];
  __shared__ unsigned short sB[2][256 * 64];
  const int tid = threadIdx.x;
  const int lane = tid & 63;
  const int wave = tid >> 6;
  const int wr = wave >> 2;  // 0..1  (M half)
  const int wc = wave & 3;   // 0..3  (N quarter)
  const int frow = lane & 15;
  const int jb = lane >> 4;  // 0..3
  const int sw = frow & 7;   // XOR swizzle key
  const int bn = blockIdx.x, bm = blockIdx.y;
  const size_t rowA0 = (size_t)bm * 256;
  const size_t rowB0 = (size_t)bn * 256;

  f32x4 acc[8][4] = {};

  // stage one half-tile (h=0/1 -> rows h*128..h*128+127) of K-tile `ktile`.
  // LDS dest linear (wave-uniform base + lane*16); XOR swizzle applied to the
  // GLOBAL source chunk (m173 pattern).
  auto stage = [&](const unsigned short* __restrict__ G, size_t row0,
                   unsigned short* dst, int h, int ktile) {
    const int kt = (ktile < 64 ? ktile : 0) << 6;  // clamp: tiles >=64 load k=0, never read
#pragma unroll
    for (int l = 0; l < 2; ++l) {
      const int c = (l << 9) + tid;          // 0..1023
      const int r = c >> 3;                  // row within half: 0..127
      const int jg = (c & 7) ^ (r & 7);      // pre-swizzled global chunk
      gl2lds16(G + (row0 + (size_t)((h << 7) + r)) * K + kt + (jg << 3),
               dst + (h << 13) + (c << 3));
    }
  };

  // one 4-phase group; r0/r1/r2 rotate over m-steps 0..7 with 2-batch lookahead
  auto group = [&](int p, int gA, int gB) {
    const unsigned short* sAp = sA[p];
    const unsigned short* sBp = sB[p];
    unsigned short* sAn = (unsigned short*)sA[p ^ 1];
    unsigned short* sBn = (unsigned short*)sB[p];
    bf16x8 bq[4][2];
    bf16x8 r0[2], r1[2], r2[2];
    // ---- phase 0: burst = bq + r0..r2 (14 reads)
    RD_A(r0, 0);
    RD_B();
    RD_A(r1, 1);
    RD_A(r2, 2);
    stage(A, rowA0, sAn, 0, gA);
    BARX(); SCHEDB();
    __builtin_amdgcn_s_setprio(1);
    MF(0, r0);
    RD_A(r0, 3);
    MF(1, r1);
    __builtin_amdgcn_s_setprio(0);
    BARX(); SCHEDB();
    // ---- phase 1
    RD_A(r1, 4);
    stage(A, rowA0, sAn, 1, gA);
    BARX(); SCHEDB();
    __builtin_amdgcn_s_setprio(1);
    MF(2, r2);
    RD_A(r2, 5);
    MF(3, r0);
    __builtin_amdgcn_s_setprio(0);
    BARX(); SCHEDB();
    // ---- phase 2
    RD_A(r0, 6);
    stage(B, rowB0, sBn, 0, gB);
    BARX(); SCHEDB();
    __builtin_amdgcn_s_setprio(1);
    MF(4, r1);
    RD_A(r1, 7);
    MF(5, r2);
    __builtin_amdgcn_s_setprio(0);
    BARX(); SCHEDB();
    // ---- phase 3 (pure MFMA; single per-K-tile vmcnt before closing barrier)
    stage(B, rowB0, sBn, 1, gB);
    BARX(); SCHEDB();
    __builtin_amdgcn_s_setprio(1);
    MF(6, r0);
    MF(7, r1);
    __builtin_amdgcn_s_setprio(0);
    WAITV4(); SCHEDB();
    BARX(); SCHEDB();
  };

  // prologue: tile0 (B then A) -> buf0, B(1) -> buf1; vmcnt(4) leaves B(1)'s
  // 4 loads in flight (steady-state entry invariant).
  stage(B, rowB0, sB[0], 0, 0);
  stage(B, rowB0, sB[0], 1, 0);
  stage(A, rowA0, sA[0], 0, 0);
  stage(A, rowA0, sA[0], 1, 0);
  stage(B, rowB0, sB[1], 0, 1);
  stage(B, rowB0, sB[1], 1, 1);
  WAITV4();
  BARX();
  SCHEDB();

#pragma unroll 1
  for (int i = 0; i < 32; ++i) {
    group(0, 2 * i + 1, 2 * i + 2);
    group(1, 2 * i + 2, 2 * i + 3);
  }

  // epilogue: C/D layout col = lane&15, row = (lane>>4)*4 + reg
  const int rbase = bm * 256 + (wr << 7) + (jb << 2);
  const int cbase = bn * 256 + (wc << 6) + frow;
#pragma unroll
  for (int m = 0; m < 8; ++m)
#pragma unroll
    for (int n = 0; n < 4; ++n) {
      float* cp = C + (size_t)(rbase + (m << 4)) * N + cbase + (n << 4);
#pragma unroll
      for (int r = 0; r < 4; ++r) cp[(size_t)r * N] = acc[m][n][r];
    }
}

// ---------------------------------------------------------------------------
// K4: per-row FWHT(4096) on fp32 output ; * SV * (1/64)
// ---------------------------------------------------------------------------
__global__ void __launch_bounds__(256) k_fwht_out(float* __restrict__ Y,
                                                  const float* __restrict__ SV) {
  __shared__ float lds[4224];
  const int t = threadIdx.x;
  const size_t row = blockIdx.x;
  float* yrow = Y + row * 4096;
  const float4* yr = (const float4*)yrow;
  float v[16];
#pragma unroll
  for (int q = 0; q < 4; ++q) {
    float4 a = yr[4 * t + q];
    v[4 * q + 0] = a.x;
    v[4 * q + 1] = a.y;
    v[4 * q + 2] = a.z;
    v[4 * q + 3] = a.w;
  }
  fwht16(v);  // bits 0-3
#pragma unroll
  for (int q = 0; q < 4; ++q) {
    int i0 = 16 * t + 4 * q;
    *(float4*)&lds[LP(i0)] = make_float4(v[4 * q], v[4 * q + 1], v[4 * q + 2], v[4 * q + 3]);
  }
  __syncthreads();
  const int b = ((t >> 4) << 8) | (t & 15);
#pragma unroll
  for (int j = 0; j < 16; ++j) { int i = b + 16 * j; v[j] = lds[LP(i)]; }
  fwht16(v);  // bits 4-7
#pragma unroll
  for (int j = 0; j < 16; ++j) { int i = b + 16 * j; lds[LP(i)] = v[j]; }
  __syncthreads();
#pragma unroll
  for (int j = 0; j < 16; ++j) { int i = t + 256 * j; v[j] = lds[LP(i)]; }
  fwht16(v);  // bits 8-11
#pragma unroll
  for (int j = 0; j < 16; ++j) {
    int i = t + 256 * j;
    yrow[i] = v[j] * SV[i] * 0.015625f;
  }
}

// ---------------------------------------------------------------------------
extern "C" void kernel_launch(void* const* d_in, const int* in_sizes, int n_in,
                              void* d_out, int out_size, void* d_ws, size_t ws_size,
                              hipStream_t stream) {
  const float* X     = (const float*)d_in[0];
  const float* SU    = (const float*)d_in[1];
  const float* SV    = (const float*)d_in[2];
  const float* G     = (const float*)d_in[3];
  const int*   Qidxs = (const int*)d_in[4];
  float* out = (float*)d_out;

  unsigned short* Xh = (unsigned short*)d_ws;
  unsigned short* Wh = Xh + (size_t)4096 * 4096;

  k_prep<<<4096 + 8192, 256, 0, stream>>>(X, SU, Xh, Qidxs, G, Wh);
  k_gemm_bt<<<dim3(16, 16), 512, 0, stream>>>(Xh, Wh, out);
  k_fwht_out<<<4096, 256, 0, stream>>>(out, SV);
}